// Round 14
// baseline (161.358 us; speedup 1.0000x reference)
//
#include <hip/hip_runtime.h>
#include <hip/hip_bf16.h>
#include <stdint.h>

typedef short bf16x8 __attribute__((ext_vector_type(8)));
typedef float f32x16 __attribute__((ext_vector_type(16)));
typedef uint32_t u32x2 __attribute__((ext_vector_type(2), aligned(4)));

#define T 2048
#define KLEN 2049
#define DK 32
#define NCO 32
#define NCI 32
#define NB 32

#define GR 2216          // padded reversed row length (covers g up to 2184)
#define SREF 2055        // x[s] lives at g = SREF - s (xr); xrs[g] = xr[g+1]
#define WT_CH 257        // 8-wide d-chunks, d in [0,2056)
#define WT_ELEMS (NCI*WT_CH*NCO*8)
#define XR_ELEMS (NB*NCI*GR)

#define WT_OFF 0
#define XR_OFF (WT_ELEMS*2)
#define XRS_OFF (XR_OFF + XR_ELEMS*2)

#define CIB 528          // bytes per ci row: 33 x 16B granules (264 elems)
#define GPC 1056         // real granules per parity copy (32 ci x 33)
#define GPCP 1088        // padded to 17 x 64-chunks (no copy-straddle)
#define CPYB 17472       // parity-copy stride: >=GPCP*16, ==64 mod 128 (bank de-alias)
#define BUFB (2*CPYB)    // 34944 per double-buffer
#define LDS_TOT (2*BUFB) // 69888 -> 2 blocks/CU; reduce reuses buf0

#define GENX_BLOCKS ((NB*NCI*GR)/256)   // 8864, exact

// ------ fused generation: SIREN -> Wt (blocks 0..256) | x -> xr/xrs (rest) --
__global__ __launch_bounds__(256) void gen(
    const float* __restrict__ rel_pos,
    const float* __restrict__ w1, const float* __restrict__ b1, const float* __restrict__ om1,
    const float* __restrict__ w2, const float* __restrict__ b2, const float* __restrict__ om2,
    const float* __restrict__ w3, const float* __restrict__ b3,
    const float* __restrict__ x,
    uint16_t* __restrict__ Wt, uint16_t* __restrict__ xr, uint16_t* __restrict__ xrs)
{
    __shared__ float h1s[8][32];
    __shared__ float h2s[8][32];
    int t = threadIdx.x;
    if (blockIdx.x < WT_CH) {
        int dchunk = blockIdx.x;             // 0..256
        int dd = t >> 5, i = t & 31;
        int d = (dchunk << 3) + dd;
        float pos = (d < KLEN) ? rel_pos[2048 - d] : 0.f;
        h1s[dd][i] = sinf(om1[0] * (w1[i] * pos + b1[i]));
        __syncthreads();
        {
            float a = b2[i];
            #pragma unroll
            for (int j = 0; j < 32; ++j) a += w2[i*32 + j] * h1s[dd][j];
            h2s[dd][i] = sinf(om2[0] * a);
        }
        __syncthreads();
        for (int r = 0; r < 4; ++r) {
            int tt = t + (r << 8);
            int ci = tt >> 5, co = tt & 31;
            int coci = (co << 5) + ci;       // w3 row index (co*CIN + ci)
            float w3r[32];
            #pragma unroll
            for (int j = 0; j < 8; ++j)
                *(float4*)&w3r[j*4] = *(const float4*)&w3[coci*32 + j*4];
            float bb = b3[coci];
            union { uint16_t u[8]; uint4 qv; } pack;
            #pragma unroll
            for (int ddd = 0; ddd < 8; ++ddd) {
                float a = bb;
                #pragma unroll
                for (int j = 0; j < 32; ++j) a += w3r[j] * h2s[ddd][j];
                if (((dchunk << 3) + ddd) >= KLEN) a = 0.f;
                __hip_bfloat16 hv = __float2bfloat16(a);
                pack.u[ddd] = *(uint16_t*)&hv;
            }
            *(uint4*)&Wt[((ci*WT_CH + dchunk)*NCO + co) << 3] = pack.qv;
        }
    } else {
        int idx = (blockIdx.x - WT_CH)*256 + t;
        if (idx >= NB*NCI*GR) return;
        int row = idx / GR;          // b*32+ci
        int g = idx - row*GR;
        int s = SREF - g;
        float v  = (s  >= 0 && s  < T) ? x[row*T + s]  : 0.f;
        int s2 = s - 1;              // value at g+1
        float v2 = (s2 >= 0 && s2 < T) ? x[row*T + s2] : 0.f;
        __hip_bfloat16 hv = __float2bfloat16(v);
        __hip_bfloat16 hv2 = __float2bfloat16(v2);
        xr[idx]  = *(uint16_t*)&hv;
        xrs[idx] = *(uint16_t*)&hv2;
    }
}

__device__ __forceinline__ void gld16(const uint16_t* g, char* l)
{
    typedef const __attribute__((address_space(1))) uint32_t GU;
    typedef __attribute__((address_space(3))) uint32_t LU;
    __builtin_amdgcn_global_load_lds((GU*)g, (LU*)l, 16, 0, 0);
}

// ---------------- causal conv: implicit-Toeplitz MFMA GEMM (r12 struct) -----
// K=4 tau-chain, 128-element k-windows. One chain per block; grid 512 = 2
// blocks/CU. Pairing: block c (long chain, 16-p windows) + c+256 (short, p+1)
// co-resident -> 17 window-units per CU. b in low 5 bits -> XCD locality.
// Per window & cii: 14 staged fragments (MM=c+2*delta) serve 32 MFMAs.
// B-fragments read as 2x ds_read2_b32 (u32x2 align4) with 2-deep rotation.
__global__ __launch_bounds__(512, 4) void conv(
    const uint16_t* __restrict__ Wt, const uint16_t* __restrict__ xr,
    const float* __restrict__ bias, float* __restrict__ out)
{
    __shared__ uint4 lds4[LDS_TOT/16];
    char* ldsb = (char*)lds4;
    float* red = (float*)lds4;            // overlaps buf0; used after final barrier
    int tid = threadIdx.x;
    int b = blockIdx.x & 31;
    int q = blockIdx.x >> 5;              // 0..15
    int p = q & 7;
    int th = (q < 8) ? (63 - (p << 2)) : ((p << 2) + 3);   // long B / short A
    int nw = (th + 1) >> 2;                                // 128-elem windows
    int g0base = 2016 - (th << 5);
    int w = tid >> 6, lane = tid & 63, n = lane & 31, hi = lane >> 5;
    int cig = w;

    // staging: 2176 idx = 2 copies x 1088 (1056 real + 32 pad); 64-idx chunks,
    // wave-uniform LDS dest (linear), per-lane global source.
    int srcE[5], dstC[5];
    #pragma unroll
    for (int k = 0; k < 5; ++k) {
        int gi = tid + (k << 9);
        if (gi < 2176) {
            int cpy = gi >= GPCP;
            int j = gi - cpy*GPCP;
            dstC[k] = cpy*CPYB + (j << 4);
            if (j < GPC) {
                int ci = (j*1986) >> 16;     // j/33 for j<1056
                int qq = j - ci*33;
                srcE[k] = (cpy ? XR_ELEMS : 0) + (b*NCI + ci)*GR + (qq << 3);
            } else srcE[k] = 0;              // pad granule: safe dummy source
        } else { srcE[k] = 0; dstC[k] = -1; }
    }

    // B-read base: o = (39 - n + 8*hi) + 16*MM; byte = ci*CIB + par*CPYB + 2*(o-par)
    int obase = 39 - n + (hi << 3);
    int par = obase & 1;
    int bbb = cig*CIB + par*CPYB + ((obase - par) << 1);

    f32x16 acc0, acc1, acc2, acc3;
    #pragma unroll
    for (int r = 0; r < 16; ++r) { acc0[r]=0.f; acc1[r]=0.f; acc2[r]=0.f; acc3[r]=0.f; }

    #define STAGE(BUF, GOFF) { \
        _Pragma("unroll") \
        for (int k = 0; k < 5; ++k) \
            if (dstC[k] >= 0) gld16(xr + srcE[k] + (GOFF), (BUF) + dstC[k]); }

    // prologue: DMA window 0 into buf0
    STAGE(ldsb, g0base)
    __syncthreads();

    for (int wi = 0; wi < nw; ++wi) {
        int cur = wi & 1;
        if (wi + 1 < nw) {                   // DMA next window into other buffer
            char* bufn = ldsb + (cur ^ 1)*BUFB;
            int g0n = g0base + ((wi + 1) << 7);
            STAGE(bufn, g0n)
        }
        int dcw = wi << 4;
        const char* rbase = ldsb + cur*BUFB + bbb;

        __builtin_amdgcn_s_setprio(1);
        #pragma unroll
        for (int cii = 0; cii < 4; ++cii) {
            int ci = (cii << 3) + cig;
            const uint16_t* aB = Wt + (((ci*WT_CH + dcw + hi)*NCO + n) << 3);
            bf16x8 av0 = *(const bf16x8*)(aB);
            bf16x8 av1 = *(const bf16x8*)(aB + 512);
            bf16x8 av2 = *(const bf16x8*)(aB + 1024);
            bf16x8 av3 = *(const bf16x8*)(aB + 1536);
            bf16x8 av4 = *(const bf16x8*)(aB + 2048);
            bf16x8 av5 = *(const bf16x8*)(aB + 2560);
            bf16x8 av6 = *(const bf16x8*)(aB + 3072);
            bf16x8 av7 = *(const bf16x8*)(aB + 3584);
            const char* pbase = rbase + cii*(8*CIB);

            #define LOADF(DST, MM) { \
                const char* pp = pbase + ((MM) << 5); \
                (DST).d[0] = *(const u32x2*)(pp); \
                (DST).d[1] = *(const u32x2*)(pp + 8); }
            #define MF(AC, AV, BV) AC = __builtin_amdgcn_mfma_f32_32x32x16_bf16(AV, BV, AC, 0,0,0);

            union FB { u32x2 d[2]; bf16x8 v; } f0, f1;
            LOADF(f0, 0)
            LOADF(f1, 1)
            MF(acc0, av0, f0.v)                                          LOADF(f0, 2)
            MF(acc0, av1, f1.v)                                          LOADF(f1, 3)
            MF(acc0, av2, f0.v) MF(acc1, av0, f0.v)                      LOADF(f0, 4)
            MF(acc0, av3, f1.v) MF(acc1, av1, f1.v)                      LOADF(f1, 5)
            MF(acc0, av4, f0.v) MF(acc1, av2, f0.v) MF(acc2, av0, f0.v)  LOADF(f0, 6)
            MF(acc0, av5, f1.v) MF(acc1, av3, f1.v) MF(acc2, av1, f1.v)  LOADF(f1, 7)
            MF(acc0, av6, f0.v) MF(acc1, av4, f0.v) MF(acc2, av2, f0.v) MF(acc3, av0, f0.v) LOADF(f0, 8)
            MF(acc0, av7, f1.v) MF(acc1, av5, f1.v) MF(acc2, av3, f1.v) MF(acc3, av1, f1.v) LOADF(f1, 9)
            MF(acc1, av6, f0.v) MF(acc2, av4, f0.v) MF(acc3, av2, f0.v)  LOADF(f0, 10)
            MF(acc1, av7, f1.v) MF(acc2, av5, f1.v) MF(acc3, av3, f1.v)  LOADF(f1, 11)
            MF(acc2, av6, f0.v) MF(acc3, av4, f0.v)                      LOADF(f0, 12)
            MF(acc2, av7, f1.v) MF(acc3, av5, f1.v)                      LOADF(f1, 13)
            MF(acc3, av6, f0.v)
            MF(acc3, av7, f1.v)
            #undef MF
            #undef LOADF
        }
        __builtin_amdgcn_s_setprio(0);
        __syncthreads();                 // drains DMA (vmcnt) + read/write fence
    }
    #undef STAGE

    // ---- reduce across 8 ci-waves + epilogue, one delta at a time ----
    #pragma unroll
    for (int dlt = 0; dlt < 4; ++dlt) {
        f32x16 a = (dlt == 0) ? acc0 : (dlt == 1) ? acc1 : (dlt == 2) ? acc2 : acc3;
        __syncthreads();
        if (w < 4) {
            #pragma unroll
            for (int r = 0; r < 16; ++r)
                red[(w*16 + r)*64 + lane] = a[r];
        }
        __syncthreads();
        if (w >= 4) {
            #pragma unroll
            for (int r = 0; r < 16; ++r)
                red[((w-4)*16 + r)*64 + lane] += a[r];
        }
        __syncthreads();
        int t0 = (th - dlt) << 5;
        #pragma unroll
        for (int h = 0; h < 2; ++h) {
            int e = tid + (h << 9);
            int lane_e = e & 63;
            int reg = e >> 6;
            float s = 0.f;
            #pragma unroll
            for (int ww = 0; ww < 4; ++ww) s += red[(ww*16 + reg)*64 + lane_e];
            int co = (reg & 3) + ((reg >> 2) << 3) + ((lane_e >> 5) << 2);
            int t = t0 + (lane_e & 31);
            out[(b*NCO + co)*T + t] = s + bias[co];
        }
    }
}

extern "C" void kernel_launch(void* const* d_in, const int* in_sizes, int n_in,
                              void* d_out, int out_size, void* d_ws, size_t ws_size,
                              hipStream_t stream)
{
    const float* x       = (const float*)d_in[0];
    const float* rel_pos = (const float*)d_in[1];
    const float* w1  = (const float*)d_in[2];
    const float* b1  = (const float*)d_in[3];
    const float* om1 = (const float*)d_in[4];
    const float* w2  = (const float*)d_in[5];
    const float* b2  = (const float*)d_in[6];
    const float* om2 = (const float*)d_in[7];
    const float* w3  = (const float*)d_in[8];
    const float* b3  = (const float*)d_in[9];
    const float* bias = (const float*)d_in[10];
    float* out = (float*)d_out;
    char* ws = (char*)d_ws;
    uint16_t* Wt  = (uint16_t*)(ws + WT_OFF);
    uint16_t* xrp = (uint16_t*)(ws + XR_OFF);
    uint16_t* xrs = (uint16_t*)(ws + XRS_OFF);

    hipLaunchKernelGGL(gen, dim3(WT_CH + GENX_BLOCKS), dim3(256), 0, stream,
                       rel_pos, w1, b1, om1, w2, b2, om2, w3, b3, x, Wt, xrp, xrs);
    hipLaunchKernelGGL(conv, dim3(NB*16), dim3(512), 0, stream, Wt, xrp, bias, out);
}

// Round 15
// 154.374 us; speedup vs baseline: 1.0452x; 1.0452x over previous
//
#include <hip/hip_runtime.h>
#include <hip/hip_bf16.h>
#include <stdint.h>

typedef short bf16x8 __attribute__((ext_vector_type(8)));
typedef float f32x16 __attribute__((ext_vector_type(16)));
typedef uint32_t u32x2 __attribute__((ext_vector_type(2), aligned(4)));

#define T 2048
#define KLEN 2049
#define DK 32
#define NCO 32
#define NCI 32
#define NB 32

#define GR 2216          // padded reversed row length (covers g up to 2192)
#define SREF 2055        // x[s] lives at g = SREF - s (xr); xrs[g] = xr[g+1]
#define WT_CH 257        // 8-wide d-chunks, d in [0,2056)
#define WT_ELEMS (NCI*WT_CH*NCO*8)
#define XR_ELEMS (NB*NCI*GR)

#define WT_OFF 0
#define XR_OFF (WT_ELEMS*2)
#define XRS_OFF (XR_OFF + XR_ELEMS*2)

// per-wave private staging: 264 granules x 16B = 4224B per window buffer
// g-linear layout: g = cpy*132 + cl*33 + q  ->  byte = g*16
#define WBUF 4352        // buffer stride (4224 + pad)
#define WREG (2*WBUF)    // per-wave region (double buffer) = 8704
#define LDS_TOT (8*WREG) // 69632 -> 2 blocks/CU; 32KB reduce overlaps

// ------ kernel-generation: SIREN -> flipped, fragment-layout W (1 blk/8 d) --
__global__ __launch_bounds__(256) void gen_w(
    const float* __restrict__ rel_pos,
    const float* __restrict__ w1, const float* __restrict__ b1, const float* __restrict__ om1,
    const float* __restrict__ w2, const float* __restrict__ b2, const float* __restrict__ om2,
    const float* __restrict__ w3, const float* __restrict__ b3,
    uint16_t* __restrict__ Wt)
{
    __shared__ float h1s[8][32];
    __shared__ float h2s[8][32];
    int t = threadIdx.x;
    int dchunk = blockIdx.x;             // 0..256
    int dd = t >> 5, i = t & 31;
    int d = (dchunk << 3) + dd;
    float pos = (d < KLEN) ? rel_pos[2048 - d] : 0.f;
    h1s[dd][i] = sinf(om1[0] * (w1[i] * pos + b1[i]));
    __syncthreads();
    {
        float a = b2[i];
        #pragma unroll
        for (int j = 0; j < 32; ++j) a += w2[i*32 + j] * h1s[dd][j];
        h2s[dd][i] = sinf(om2[0] * a);
    }
    __syncthreads();
    for (int r = 0; r < 4; ++r) {
        int tt = t + (r << 8);
        int ci = tt >> 5, co = tt & 31;
        int coci = (co << 5) + ci;       // w3 row index (co*CIN + ci)
        float w3r[32];
        #pragma unroll
        for (int j = 0; j < 8; ++j)
            *(float4*)&w3r[j*4] = *(const float4*)&w3[coci*32 + j*4];
        float bb = b3[coci];
        union { uint16_t u[8]; uint4 qv; } pack;
        #pragma unroll
        for (int ddd = 0; ddd < 8; ++ddd) {
            float a = bb;
            #pragma unroll
            for (int j = 0; j < 32; ++j) a += w3r[j] * h2s[ddd][j];
            if (((dchunk << 3) + ddd) >= KLEN) a = 0.f;
            __hip_bfloat16 hv = __float2bfloat16(a);
            pack.u[ddd] = *(uint16_t*)&hv;
        }
        *(uint4*)&Wt[((ci*WT_CH + dchunk)*NCO + co) << 3] = pack.qv;
    }
}

// ---------------- x -> reversed, zero-padded bf16 (plus shifted copy) -------
__global__ __launch_bounds__(256) void gen_x(const float* __restrict__ x,
                                             uint16_t* __restrict__ xr,
                                             uint16_t* __restrict__ xrs)
{
    int idx = blockIdx.x*256 + threadIdx.x;
    if (idx >= NB*NCI*GR) return;
    int row = idx / GR;          // b*32+ci
    int g = idx - row*GR;
    int s = SREF - g;
    float v  = (s  >= 0 && s  < T) ? x[row*T + s]  : 0.f;
    int s2 = s - 1;              // value at g+1
    float v2 = (s2 >= 0 && s2 < T) ? x[row*T + s2] : 0.f;
    __hip_bfloat16 hv = __float2bfloat16(v);
    __hip_bfloat16 hv2 = __float2bfloat16(v2);
    xr[idx]  = *(uint16_t*)&hv;
    xrs[idx] = *(uint16_t*)&hv2;
}

__device__ __forceinline__ void gld16(const uint16_t* g, char* l)
{
    typedef const __attribute__((address_space(1))) uint32_t GU;
    typedef __attribute__((address_space(3))) uint32_t LU;
    __builtin_amdgcn_global_load_lds((GU*)g, (LU*)l, 16, 0, 0);
}

// ---------------- causal conv: implicit-Toeplitz MFMA GEMM ------------------
// K=4 tau-chain, 128-elem windows, BARRIER-FREE K-loop: each wave DMAs its
// own 4 ci rows (2 parity copies, 264 granules = 5 full-wave chunk loads,
// chunk 4 overlap-redundant) into a private double-buffered LDS region and
// synchronizes only via counted s_waitcnt vmcnt(5). No __syncthreads until
// the final reduce. Grid 512 = 2 blocks/CU, q/q+8 chain pairing (17 units).
__global__ __launch_bounds__(512, 4) void conv(
    const uint16_t* __restrict__ Wt, const uint16_t* __restrict__ xr,
    const float* __restrict__ bias, float* __restrict__ out)
{
    __shared__ uint4 lds4[LDS_TOT/16];
    char* ldsb = (char*)lds4;
    float* red = (float*)lds4;            // 32KB reduce area, used after K-loop
    int tid = threadIdx.x;
    int b = blockIdx.x & 31;
    int q = blockIdx.x >> 5;              // 0..15
    int p = q & 7;
    int th = (q < 8) ? (63 - (p << 2)) : ((p << 2) + 3);   // long / short chain
    int nw = (th + 1) >> 2;                                // 128-elem windows
    int g0base = 2016 - (th << 5);
    int w = tid >> 6, lane = tid & 63, n = lane & 31, hi = lane >> 5;
    int cig = w;
    char* wbase = ldsb + w*WREG;

    // per-wave staging descriptors: chunk k covers granules g = 64k+lane
    // (k<4) or 200+lane (k=4, overlaps chunk 3 -- benign double-write).
    // g -> (cpy, cl, qq): cpy = g>=132, r = g-132cpy, cl = r/33, qq = r%33.
    int srcE[5];
    #pragma unroll
    for (int k = 0; k < 5; ++k) {
        int g = (k < 4) ? (k*64 + lane) : (200 + lane);
        int cpy = g >= 132;
        int r = g - 132*cpy;
        int cl = (r*1986) >> 16;         // r/33 (valid r<1056)
        int qq = r - cl*33;
        srcE[k] = cpy*XR_ELEMS + (b*NCI + (cl << 3) + cig)*GR + (qq << 3);
    }

    // B-read base: o = (39 - n + 8*hi) + 16*MM
    // byte in buffer = par*2112 + (o-par)*2 + cl*528 + MM*32
    int obase = 39 - n + (hi << 3);
    int par = obase & 1;
    int bbb = par*2112 + ((obase - par) << 1);

    f32x16 acc0, acc1, acc2, acc3;
    #pragma unroll
    for (int r = 0; r < 16; ++r) { acc0[r]=0.f; acc1[r]=0.f; acc2[r]=0.f; acc3[r]=0.f; }

    #define STAGEW(BUF, GOFF) { \
        gld16(xr + srcE[0] + (GOFF), (BUF));          \
        gld16(xr + srcE[1] + (GOFF), (BUF) + 1024);   \
        gld16(xr + srcE[2] + (GOFF), (BUF) + 2048);   \
        gld16(xr + srcE[3] + (GOFF), (BUF) + 3072);   \
        gld16(xr + srcE[4] + (GOFF), (BUF) + 3200); }

    // prologue: DMA window 0 into buf0 (no wait yet)
    STAGEW(wbase, g0base)

    for (int wi = 0; wi < nw; ++wi) {
        int cur = wi & 1;
        if (wi + 1 < nw) {                   // DMA next window into other buffer
            char* bufn = wbase + (cur ^ 1)*WBUF;
            int g0n = g0base + ((wi + 1) << 7);
            STAGEW(bufn, g0n)
            asm volatile("s_waitcnt vmcnt(5)" ::: "memory");  // drain DMA(wi) only
        } else {
            asm volatile("s_waitcnt vmcnt(0)" ::: "memory");
        }
        int dcw = wi << 4;
        const char* rbase = wbase + cur*WBUF + bbb;

        #pragma unroll
        for (int cii = 0; cii < 4; ++cii) {
            int ci = (cii << 3) + cig;
            const uint16_t* aB = Wt + (((ci*WT_CH + dcw + hi)*NCO + n) << 3);
            bf16x8 av0 = *(const bf16x8*)(aB);
            bf16x8 av1 = *(const bf16x8*)(aB + 512);
            bf16x8 av2 = *(const bf16x8*)(aB + 1024);
            bf16x8 av3 = *(const bf16x8*)(aB + 1536);
            bf16x8 av4 = *(const bf16x8*)(aB + 2048);
            bf16x8 av5 = *(const bf16x8*)(aB + 2560);
            bf16x8 av6 = *(const bf16x8*)(aB + 3072);
            bf16x8 av7 = *(const bf16x8*)(aB + 3584);
            const char* pbase = rbase + cii*528;

            #define LOADF(DST, MM) { \
                const char* pp = pbase + ((MM) << 5); \
                (DST).d[0] = *(const u32x2*)(pp); \
                (DST).d[1] = *(const u32x2*)(pp + 8); }
            #define MF(AC, AV, BV) AC = __builtin_amdgcn_mfma_f32_32x32x16_bf16(AV, BV, AC, 0,0,0);

            union FB { u32x2 d[2]; bf16x8 v; } f0, f1;
            LOADF(f0, 0)
            LOADF(f1, 1)
            MF(acc0, av0, f0.v)                                          LOADF(f0, 2)
            MF(acc0, av1, f1.v)                                          LOADF(f1, 3)
            MF(acc0, av2, f0.v) MF(acc1, av0, f0.v)                      LOADF(f0, 4)
            MF(acc0, av3, f1.v) MF(acc1, av1, f1.v)                      LOADF(f1, 5)
            MF(acc0, av4, f0.v) MF(acc1, av2, f0.v) MF(acc2, av0, f0.v)  LOADF(f0, 6)
            MF(acc0, av5, f1.v) MF(acc1, av3, f1.v) MF(acc2, av1, f1.v)  LOADF(f1, 7)
            MF(acc0, av6, f0.v) MF(acc1, av4, f0.v) MF(acc2, av2, f0.v) MF(acc3, av0, f0.v) LOADF(f0, 8)
            MF(acc0, av7, f1.v) MF(acc1, av5, f1.v) MF(acc2, av3, f1.v) MF(acc3, av1, f1.v) LOADF(f1, 9)
            MF(acc1, av6, f0.v) MF(acc2, av4, f0.v) MF(acc3, av2, f0.v)  LOADF(f0, 10)
            MF(acc1, av7, f1.v) MF(acc2, av5, f1.v) MF(acc3, av3, f1.v)  LOADF(f1, 11)
            MF(acc2, av6, f0.v) MF(acc3, av4, f0.v)                      LOADF(f0, 12)
            MF(acc2, av7, f1.v) MF(acc3, av5, f1.v)                      LOADF(f1, 13)
            MF(acc3, av6, f0.v)
            MF(acc3, av7, f1.v)
            #undef MF
            #undef LOADF
        }
    }
    #undef STAGEW

    // ---- reduce across 8 ci-waves + epilogue, one delta at a time ----
    #pragma unroll
    for (int dlt = 0; dlt < 4; ++dlt) {
        f32x16 a = (dlt == 0) ? acc0 : (dlt == 1) ? acc1 : (dlt == 2) ? acc2 : acc3;
        __syncthreads();
        if (w < 4) {
            #pragma unroll
            for (int r = 0; r < 16; ++r)
                red[(w*16 + r)*64 + lane] = a[r];
        }
        __syncthreads();
        if (w >= 4) {
            #pragma unroll
            for (int r = 0; r < 16; ++r)
                red[((w-4)*16 + r)*64 + lane] += a[r];
        }
        __syncthreads();
        int t0 = (th - dlt) << 5;
        #pragma unroll
        for (int h = 0; h < 2; ++h) {
            int e = tid + (h << 9);
            int lane_e = e & 63;
            int reg = e >> 6;
            float s = 0.f;
            #pragma unroll
            for (int ww = 0; ww < 4; ++ww) s += red[(ww*16 + reg)*64 + lane_e];
            int co = (reg & 3) + ((reg >> 2) << 3) + ((lane_e >> 5) << 2);
            int t = t0 + (lane_e & 31);
            out[(b*NCO + co)*T + t] = s + bias[co];
        }
    }
}

extern "C" void kernel_launch(void* const* d_in, const int* in_sizes, int n_in,
                              void* d_out, int out_size, void* d_ws, size_t ws_size,
                              hipStream_t stream)
{
    const float* x       = (const float*)d_in[0];
    const float* rel_pos = (const float*)d_in[1];
    const float* w1  = (const float*)d_in[2];
    const float* b1  = (const float*)d_in[3];
    const float* om1 = (const float*)d_in[4];
    const float* w2  = (const float*)d_in[5];
    const float* b2  = (const float*)d_in[6];
    const float* om2 = (const float*)d_in[7];
    const float* w3  = (const float*)d_in[8];
    const float* b3  = (const float*)d_in[9];
    const float* bias = (const float*)d_in[10];
    float* out = (float*)d_out;
    char* ws = (char*)d_ws;
    uint16_t* Wt  = (uint16_t*)(ws + WT_OFF);
    uint16_t* xrp = (uint16_t*)(ws + XR_OFF);
    uint16_t* xrs = (uint16_t*)(ws + XRS_OFF);

    hipLaunchKernelGGL(gen_w, dim3(WT_CH), dim3(256), 0, stream,
                       rel_pos, w1, b1, om1, w2, b2, om2, w3, b3, Wt);
    int n2 = NB*NCI*GR;
    hipLaunchKernelGGL(gen_x, dim3((n2+255)/256), dim3(256), 0, stream, x, xrp, xrs);
    hipLaunchKernelGGL(conv, dim3(NB*16), dim3(512), 0, stream, Wt, xrp, bias, out);
}